// Round 6
// baseline (466.688 us; speedup 1.0000x reference)
//
#include <hip/hip_runtime.h>

#define HIDDEN 64
#define NB 32
#define SCAN_BLOCK 1024
#define HSTR 72   // LDS H-tile row stride in shorts: %8==0 (16B align for b128)

typedef __attribute__((ext_vector_type(8))) short bf16x8;
typedef __attribute__((ext_vector_type(4))) float f32x4;

// ---- bf16 helpers (RNE) ----
static __device__ __forceinline__ unsigned short f2bf(float x) {
    union { float f; unsigned u; } v; v.f = x;
    unsigned r = v.u + 0x7fffu + ((v.u >> 16) & 1u);
    return (unsigned short)(r >> 16);
}
static __device__ __forceinline__ float bf2f(unsigned short s) {
    union { unsigned u; float f; } v; v.u = ((unsigned)s) << 16;
    return v.f;
}

// ---------------------------------------------------------------------------
// Feature pack + histogram + output zeroing.
// feat[n][lane] = {scalar, v0, v1, v2} as bf16x4 (8 B). First E threads also
// count destination rows (counts pre-zeroed by memset). Thread i also zeroes
// out[(float4)i] -- total == N*64 == out_size/16 exactly, so the fused
// kernel's atomics land on zeroed memory (stream-ordered).
// ---------------------------------------------------------------------------
__global__ __launch_bounds__(256) void featpack_kernel(
    const float* __restrict__ scalar,     // [N,64]
    const float* __restrict__ vector,     // [N,3,64]
    const int*   __restrict__ edge_index, // [2,E] (row part used for hist)
    int* __restrict__ counts,             // [N] pre-zeroed
    ushort4* __restrict__ feat,           // [N*64]
    float4* __restrict__ out_zero,        // d_out viewed as float4[N*64]
    int total, int E)
{
    int i = blockIdx.x * 256 + threadIdx.x;
    if (i < E) atomicAdd(&counts[edge_index[i]], 1);
    if (i >= total) return;
    const float4 z = {0.f, 0.f, 0.f, 0.f};
    out_zero[i] = z;
    const int n = i >> 6, l = i & 63;
    const float* vp = vector + (size_t)n * 192 + l;
    ushort4 o;
    o.x = f2bf(scalar[i]);
    o.y = f2bf(vp[0]);
    o.z = f2bf(vp[64]);
    o.w = f2bf(vp[128]);
    feat[i] = o;
}

// ---------------------------------------------------------------------------
// CSR scan: 3-pass multi-block.
// ---------------------------------------------------------------------------
__global__ __launch_bounds__(SCAN_BLOCK) void scan_pass1(
    const int* __restrict__ counts, int* __restrict__ partial,
    int* __restrict__ blocksums, int N)
{
    __shared__ int tmp[SCAN_BLOCK];
    const int t = threadIdx.x;
    const int gid = blockIdx.x * SCAN_BLOCK + t;
    int v = (gid < N) ? counts[gid] : 0;
    tmp[t] = v;
    __syncthreads();
    for (int off = 1; off < SCAN_BLOCK; off <<= 1) {
        int x = (t >= off) ? tmp[t - off] : 0;
        __syncthreads();
        tmp[t] += x;
        __syncthreads();
    }
    if (gid < N) partial[gid] = tmp[t] - v;
    if (t == SCAN_BLOCK - 1) blocksums[blockIdx.x] = tmp[t];
}

__global__ __launch_bounds__(64) void scan_pass2(int* __restrict__ blocksums, int nb)
{
    const int t = threadIdx.x;
    int v = (t < nb) ? blocksums[t] : 0;
    int s = v;
    #pragma unroll
    for (int off = 1; off < 64; off <<= 1) {
        int x = __shfl_up(s, off, 64);
        if (t >= off) s += x;
    }
    if (t < nb) blocksums[t] = s - v;   // exclusive
}

__global__ __launch_bounds__(SCAN_BLOCK) void scan_pass3(
    const int* __restrict__ partial, const int* __restrict__ blocksums,
    int* __restrict__ offsets, int* __restrict__ cursors, int N, int E)
{
    const int gid = blockIdx.x * SCAN_BLOCK + threadIdx.x;
    if (gid < N) {
        int o = partial[gid] + blocksums[blockIdx.x];
        offsets[gid] = o;
        cursors[gid] = o;
    }
    if (blockIdx.x == 0 && threadIdx.x == 0) offsets[N] = E;
}

// Scatter: per edge, claim CSR slot p; record source column, dest row, and
// forward permutation eperm[p] = e. Phase A reads edges in CSR order
// (random reads of L3-resident edge_length) and consumes W from LDS.
__global__ __launch_bounds__(256) void scatter_kernel(
    const int* __restrict__ edge_index, int* __restrict__ cursors,
    int* __restrict__ cols, int* __restrict__ rows,
    int* __restrict__ eperm, int E)
{
    int i = blockIdx.x * 256 + threadIdx.x;
    if (i < E) {
        const int r = edge_index[i];
        int p = atomicAdd(&cursors[r], 1);
        cols[p] = edge_index[E + i];
        rows[p] = r;
        eperm[p] = i;
    }
}

// ---------------------------------------------------------------------------
// FUSED kernel: per 64-slot CSR chunk -- MFMA MLP (both s and v) with the
// W tile kept in LDS, then immediately consumed by the CSR-segment
// accumulate loop (round-5's 1-ahead shfl structure). Segment flushes are
// wave-uniform atomicAdd (CSR-sorted => ~7 segments/chunk). Eliminates the
// 125 MB W write + 128 MB W read + node kernel launch, and keeps the
// 25.6 MB feat table L3-resident (no longer evicted by the W stream).
// ---------------------------------------------------------------------------
__global__ __launch_bounds__(256) void fused_kernel(
    const float* __restrict__ edge_length,   // [E,32]
    const int*   __restrict__ eperm,         // [E] edge id at CSR slot p
    const int*   __restrict__ cols,          // [E] source node per CSR slot
    const int*   __restrict__ rows,          // [E] dest node per CSR slot
    const ushort4* __restrict__ feat,        // [N*64] bf16 {s,v0,v1,v2}
    const float* __restrict__ sw1, const float* __restrict__ sb1,
    const float* __restrict__ sw2, const float* __restrict__ sb2,
    const float* __restrict__ vw1, const float* __restrict__ vb1,
    const float* __restrict__ vw2, const float* __restrict__ vb2,
    float* __restrict__ out_scalar,          // [N,64]  (pre-zeroed)
    float* __restrict__ out_vector,          // [N,3,64] (pre-zeroed)
    int E, int nchunks)
{
    __shared__ short Hs[4][64 * HSTR];       // per-wave staging

    const int t    = threadIdx.x;
    const int lane = t & 63;
    const int wid  = t >> 6;
    const int quad = lane >> 4;
    const int l16  = lane & 15;
    short* Hw = Hs[wid];

    const float* w1p[2] = {sw1, vw1};
    const float* b1p[2] = {sb1, vb1};
    const float* w2p[2] = {sw2, vw2};
    const float* b2p[2] = {sb2, vb2};

    // ---- weight B-frags resident in VGPRs ----
    bf16x8 w1f[2][4];
    bf16x8 w2f[2][2][4];
    float  b1v[2][4], b2v[2][4];
    #pragma unroll
    for (int m = 0; m < 2; ++m) {
        #pragma unroll
        for (int nt = 0; nt < 4; ++nt) {
            const int col = nt * 16 + l16;
            #pragma unroll
            for (int j = 0; j < 8; ++j)
                w1f[m][nt][j] = (short)f2bf(w1p[m][(quad * 8 + j) * HIDDEN + col]);
            #pragma unroll
            for (int kk = 0; kk < 2; ++kk) {
                #pragma unroll
                for (int j = 0; j < 8; ++j)
                    w2f[m][kk][nt][j] = (short)f2bf(w2p[m][(kk * 32 + quad * 8 + j) * HIDDEN + col]);
            }
            b1v[m][nt] = b1p[m][col];
            b2v[m][nt] = b2p[m][col];
        }
    }

    const int wave_g = blockIdx.x * 4 + wid;
    const int nwaves = gridDim.x * 4;

    for (int c = wave_g; c < nchunks; c += nwaves) {
        const int j0  = c * 64;
        const int cnt = (E - j0 < 64) ? (E - j0) : 64;

        // per-lane CSR metadata for this chunk (one coalesced load each)
        int mycol = 0, myrow = 0;
        if (lane < cnt) {
            mycol = cols[j0 + lane];
            myrow = rows[j0 + lane];
        }

        // ---- A-frags: 64 CSR slots -> gathered edge rows (L3-resident) ----
        bf16x8 af[4];
        #pragma unroll
        for (int mt = 0; mt < 4; ++mt) {
            int p = j0 + mt * 16 + l16;
            if (p >= E) p = E - 1;
            const int e = eperm[p];
            const float* r = edge_length + (size_t)e * NB + quad * 8;
            float4 u0 = *(const float4*)r;
            float4 u1 = *(const float4*)(r + 4);
            af[mt][0] = (short)f2bf(u0.x); af[mt][1] = (short)f2bf(u0.y);
            af[mt][2] = (short)f2bf(u0.z); af[mt][3] = (short)f2bf(u0.w);
            af[mt][4] = (short)f2bf(u1.x); af[mt][5] = (short)f2bf(u1.y);
            af[mt][6] = (short)f2bf(u1.z); af[mt][7] = (short)f2bf(u1.w);
        }

        #pragma unroll
        for (int m = 0; m < 2; ++m) {
            // ---- layer 1 + SiLU -> LDS bf16 ----
            #pragma unroll
            for (int mt = 0; mt < 4; ++mt) {
                #pragma unroll
                for (int nt = 0; nt < 4; ++nt) {
                    f32x4 cf = {b1v[m][nt], b1v[m][nt], b1v[m][nt], b1v[m][nt]};
                    cf = __builtin_amdgcn_mfma_f32_16x16x32_bf16(af[mt], w1f[m][nt], cf, 0, 0, 0);
                    #pragma unroll
                    for (int r4 = 0; r4 < 4; ++r4) {
                        float x = cf[r4];
                        // silu via fast rcp: result is rounded to bf16 anyway
                        x = x * __builtin_amdgcn_rcpf(1.0f + __expf(-x));
                        const int row = mt * 16 + quad * 4 + r4;
                        Hw[row * HSTR + nt * 16 + l16] = (short)f2bf(x);
                    }
                }
            }

            // ---- layer 2 -> LDS bf16 (W tile for this m stays in LDS) ----
            #pragma unroll
            for (int mt = 0; mt < 4; ++mt) {
                const int arow = mt * 16 + l16;
                bf16x8 a0 = *(const bf16x8*)(Hw + arow * HSTR + quad * 8);
                bf16x8 a1 = *(const bf16x8*)(Hw + arow * HSTR + 32 + quad * 8);
                #pragma unroll
                for (int nt = 0; nt < 4; ++nt) {
                    f32x4 cf = {b2v[m][nt], b2v[m][nt], b2v[m][nt], b2v[m][nt]};
                    cf = __builtin_amdgcn_mfma_f32_16x16x32_bf16(a1, w2f[m][1][nt], cf, 0, 0, 0);
                    cf = __builtin_amdgcn_mfma_f32_16x16x32_bf16(a0, w2f[m][0][nt], cf, 0, 0, 0);
                    #pragma unroll
                    for (int r4 = 0; r4 < 4; ++r4) {
                        const int row = mt * 16 + quad * 4 + r4;
                        Hw[row * HSTR + nt * 16 + l16] = (short)f2bf(cf[r4]);
                    }
                }
            }

            // ---- accumulate pass for this m: consume W from LDS ----
            // 1-ahead prefetch; node/col via __shfl -> scalar regs; flushes
            // are wave-uniform (shfl'd node), CSR-sorted so ~7 per chunk.
            if (m == 0) {
                int node_cur = __shfl(myrow, 0, 64);
                const int c0 = __shfl(mycol, 0, 64);
                float wcur = bf2f((unsigned short)Hw[lane]);          // row 0
                ushort4 f = feat[(size_t)c0 * 64 + lane];
                float acc = 0.f;
                for (int k = 0; k < cnt; ++k) {
                    const int kn = (k + 1 < cnt) ? k + 1 : k;
                    const float wn = bf2f((unsigned short)Hw[kn * HSTR + lane]);
                    const int cn = __shfl(mycol, kn, 64);
                    const ushort4 fn = feat[(size_t)cn * 64 + lane];
                    const int node_n = (k + 1 < cnt) ? __shfl(myrow, kn, 64) : -1;
                    acc = fmaf(bf2f(f.x), wcur, acc);
                    if (node_n != node_cur) {
                        atomicAdd(out_scalar + (size_t)node_cur * HIDDEN + lane, acc);
                        acc = 0.f;
                        node_cur = node_n;
                    }
                    wcur = wn; f = fn;
                }
            } else {
                int node_cur = __shfl(myrow, 0, 64);
                const int c0 = __shfl(mycol, 0, 64);
                float wcur = bf2f((unsigned short)Hw[lane]);          // row 0
                ushort4 f = feat[(size_t)c0 * 64 + lane];
                float a0 = 0.f, a1 = 0.f, a2 = 0.f;
                for (int k = 0; k < cnt; ++k) {
                    const int kn = (k + 1 < cnt) ? k + 1 : k;
                    const float wn = bf2f((unsigned short)Hw[kn * HSTR + lane]);
                    const int cn = __shfl(mycol, kn, 64);
                    const ushort4 fn = feat[(size_t)cn * 64 + lane];
                    const int node_n = (k + 1 < cnt) ? __shfl(myrow, kn, 64) : -1;
                    a0 = fmaf(bf2f(f.y), wcur, a0);
                    a1 = fmaf(bf2f(f.z), wcur, a1);
                    a2 = fmaf(bf2f(f.w), wcur, a2);
                    if (node_n != node_cur) {
                        float* ov = out_vector + (size_t)node_cur * 192;
                        atomicAdd(ov + lane,        a0);
                        atomicAdd(ov + 64 + lane,   a1);
                        atomicAdd(ov + 128 + lane,  a2);
                        a0 = 0.f; a1 = 0.f; a2 = 0.f;
                        node_cur = node_n;
                    }
                    wcur = wn; f = fn;
                }
            }
        }
    }
}

extern "C" void kernel_launch(void* const* d_in, const int* in_sizes, int n_in,
                              void* d_out, int out_size, void* d_ws, size_t ws_size,
                              hipStream_t stream) {
    const float* scalar      = (const float*)d_in[0];
    const float* vector      = (const float*)d_in[1];
    // d_in[2] = edge_sh (unused by reference)
    const float* edge_length = (const float*)d_in[3];
    const int*   edge_index  = (const int*)d_in[4];
    const float* sw1 = (const float*)d_in[5];
    const float* sb1 = (const float*)d_in[6];
    const float* sw2 = (const float*)d_in[7];
    const float* sb2 = (const float*)d_in[8];
    const float* vw1 = (const float*)d_in[9];
    const float* vb1 = (const float*)d_in[10];
    const float* vw2 = (const float*)d_in[11];
    const float* vb2 = (const float*)d_in[12];

    const int N = in_sizes[0] / HIDDEN;       // 50000
    const int E = in_sizes[4] / 2;            // 500000

    float* out_scalar = (float*)d_out;
    float* out_vector = (float*)d_out + (size_t)N * HIDDEN;

    // ---- workspace layout (W eliminated -- fused kernel consumes LDS W) ----
    size_t off = 0;
    int* cols = (int*)((char*)d_ws + off);                // [E]
    off += (size_t)E * 4;
    int* rows = (int*)((char*)d_ws + off);                // [E]
    off += (size_t)E * 4;
    int* eperm = (int*)((char*)d_ws + off);               // [E]
    off += (size_t)E * 4;
    int* ib = (int*)((char*)d_ws + off);
    int* counts    = ib;                                  // [N]
    int* partial   = ib + N;                              // [N]
    int* offsets   = ib + 2 * N;                          // [N+1]
    int* cursors   = ib + 3 * N + 1;                      // [N]
    int* blocksums = ib + 4 * N + 1;                      // [64]
    off += ((size_t)4 * N + 1 + 64) * 4;
    off = (off + 15) & ~(size_t)15;
    ushort4* feat = (ushort4*)((char*)d_ws + off);        // [N*64] = 25.6 MB

    hipMemsetAsync(counts, 0, (size_t)N * sizeof(int), stream);

    const int egrid = (E + 255) / 256;
    const int total = N * 64;

    // featpack + histogram + output zeroing (out float4 count == total)
    featpack_kernel<<<(total + 255) / 256, 256, 0, stream>>>(
        scalar, vector, edge_index, counts, feat, (float4*)d_out, total, E);

    // CSR scan (3-pass, multi-block) + scatter (cols/rows + forward perm)
    const int nb = (N + SCAN_BLOCK - 1) / SCAN_BLOCK;     // 49 (<=64 for pass2)
    scan_pass1<<<nb, SCAN_BLOCK, 0, stream>>>(counts, partial, blocksums, N);
    scan_pass2<<<1, 64, 0, stream>>>(blocksums, nb);
    scan_pass3<<<nb, SCAN_BLOCK, 0, stream>>>(partial, blocksums, offsets, cursors, N, E);
    scatter_kernel<<<egrid, 256, 0, stream>>>(edge_index, cursors, cols, rows, eperm, E);

    // Fused MLP + segment-accumulate over CSR slots.
    const int nchunks = (E + 63) / 64;
    fused_kernel<<<1024, 256, 0, stream>>>(
        edge_length, eperm, cols, rows, feat,
        sw1, sb1, sw2, sb2, vw1, vb1, vw2, vb2,
        out_scalar, out_vector, E, nchunks);
}

// Round 7
// 433.395 us; speedup vs baseline: 1.0768x; 1.0768x over previous
//
#include <hip/hip_runtime.h>
#include <hip/hip_cooperative_groups.h>

namespace cg = cooperative_groups;

#define HIDDEN 64
#define NB 32
#define HSTR 72        // LDS H-tile row stride in shorts: %8==0 (16B align for b128)
#define CS_THREADS 512 // coop scan/scatter block (8 waves -> trivially co-resident)
#define CS_BLOCKS 256  // 1 block/CU

typedef __attribute__((ext_vector_type(8))) short bf16x8;
typedef __attribute__((ext_vector_type(4))) float f32x4;
typedef __attribute__((ext_vector_type(8))) unsigned short u16x8;

// ---- bf16 helpers (RNE) ----
static __device__ __forceinline__ unsigned short f2bf(float x) {
    union { float f; unsigned u; } v; v.f = x;
    unsigned r = v.u + 0x7fffu + ((v.u >> 16) & 1u);
    return (unsigned short)(r >> 16);
}
static __device__ __forceinline__ float bf2f(unsigned short s) {
    union { unsigned u; float f; } v; v.u = ((unsigned)s) << 16;
    return v.f;
}

// ---------------------------------------------------------------------------
// Feature pack (x2 vectorized) + histogram.
// Thread handles elements {2i, 2i+1}: since 2i is even, both elements share
// the same node row (l even, l+1 <= 63), so loads are float2 and the feat
// store is one 16 B u16x8. First E/2 threads also do 2 hist atomics.
// ---------------------------------------------------------------------------
__global__ __launch_bounds__(256) void featpack_kernel(
    const float* __restrict__ scalar,     // [N,64]
    const float* __restrict__ vector,     // [N,3,64]
    const int*   __restrict__ edge_index, // [2,E] (row part used for hist)
    int* __restrict__ counts,             // [N] pre-zeroed
    u16x8* __restrict__ featv,            // [N*32] = feat as 16 B packs
    int total, int E, int do_feat)
{
    const int idx   = blockIdx.x * 256 + threadIdx.x;
    const int base2 = idx * 2;
    if (base2 < E)     atomicAdd(&counts[edge_index[base2]], 1);
    if (base2 + 1 < E) atomicAdd(&counts[edge_index[base2 + 1]], 1);
    if (!do_feat || base2 >= total) return;
    const int n = base2 >> 6, l = base2 & 63;
    const float* vp = vector + (size_t)n * 192 + l;
    const float2 s2 = *(const float2*)(scalar + base2);
    const float2 w0 = *(const float2*)(vp);
    const float2 w1 = *(const float2*)(vp + 64);
    const float2 w2 = *(const float2*)(vp + 128);
    u16x8 o;
    o[0] = f2bf(s2.x); o[1] = f2bf(w0.x); o[2] = f2bf(w1.x); o[3] = f2bf(w2.x);
    o[4] = f2bf(s2.y); o[5] = f2bf(w0.y); o[6] = f2bf(w1.y); o[7] = f2bf(w2.y);
    featv[idx] = o;
}

// ---------------------------------------------------------------------------
// Cooperative scan + scatter: replaces 4 dispatches (scan1/2/3 + scatter).
// Unlike round-4's failed coop prep, the phases here are TINY (50k-element
// scan) and the only bulk phase (scatter, 500k edges) runs grid-strided over
// 131k threads (~4 edges/thread). 256 blocks x 512 threads = 8 waves/CU,
// co-residency guaranteed. Requires N < CS_BLOCKS*CS_THREADS (= 131072).
// ---------------------------------------------------------------------------
__global__ __launch_bounds__(CS_THREADS) void scan_scatter_kernel(
    const int* __restrict__ edge_index,   // [2,E]
    const int* __restrict__ counts,       // [N]
    int* __restrict__ offsets,            // [N+1]
    int* __restrict__ cursors,            // [N]
    int* __restrict__ blocksums,          // [CS_BLOCKS]
    int* __restrict__ cols,               // [E]
    int* __restrict__ eperm,              // [E]
    int N, int E)
{
    cg::grid_group grid = cg::this_grid();
    __shared__ int tmp[CS_THREADS];
    const int t   = threadIdx.x;
    const int gid = blockIdx.x * CS_THREADS + t;

    // P1: block-local inclusive scan of this block's 512-element chunk
    int v = (gid < N) ? counts[gid] : 0;
    tmp[t] = v;
    __syncthreads();
    for (int off = 1; off < CS_THREADS; off <<= 1) {
        int x = (t >= off) ? tmp[t - off] : 0;
        __syncthreads();
        tmp[t] += x;
        __syncthreads();
    }
    const int excl = tmp[t] - v;            // exclusive within block
    if (t == CS_THREADS - 1) blocksums[blockIdx.x] = tmp[t];
    grid.sync();

    // P2: block 0 scans the CS_BLOCKS partial sums (exclusive)
    if (blockIdx.x == 0) {
        int b = (t < CS_BLOCKS) ? blocksums[t] : 0;
        tmp[t] = b;
        __syncthreads();
        for (int off = 1; off < CS_THREADS; off <<= 1) {
            int x = (t >= off) ? tmp[t - off] : 0;
            __syncthreads();
            tmp[t] += x;
            __syncthreads();
        }
        if (t < CS_BLOCKS) blocksums[t] = tmp[t] - b;
    }
    grid.sync();

    // P3: offsets + cursors
    if (gid < N) {
        const int o = excl + blocksums[blockIdx.x];
        offsets[gid] = o;
        cursors[gid] = o;
    }
    if (gid == N) offsets[N] = E;
    grid.sync();

    // P4: scatter -- claim CSR slot p; record source col + forward perm
    const int nth = CS_BLOCKS * CS_THREADS;
    for (int i = gid; i < E; i += nth) {
        const int r = edge_index[i];
        int p = atomicAdd(&cursors[r], 1);
        cols[p] = edge_index[E + i];
        eperm[p] = i;
    }
}

// ---------------------------------------------------------------------------
// Phase A (MFMA, CSR slot order): gathers edge_length rows via eperm
// (L3-resident -> round-3/5 FETCH 33 MB), writes W rows SEQUENTIALLY
// (WRITE exactly 125 MB, no write-allocate amplification). Verbatim round 5.
// W[p][0..63] = scalar-MLP weights, W[p][64..127] = vector-MLP weights (bf16).
// ---------------------------------------------------------------------------
__global__ __launch_bounds__(256) void mlp_mfma_kernel(
    const float* __restrict__ edge_length,   // [E,32]
    const int*   __restrict__ eperm,         // [E] edge id at CSR slot p
    const float* __restrict__ sw1, const float* __restrict__ sb1,
    const float* __restrict__ sw2, const float* __restrict__ sb2,
    const float* __restrict__ vw1, const float* __restrict__ vb1,
    const float* __restrict__ vw2, const float* __restrict__ vb2,
    unsigned short* __restrict__ W,          // [E,128] bf16, CSR row order
    int E, int nchunks)
{
    __shared__ short Hs[4][64 * HSTR];       // per-wave staging

    const int t    = threadIdx.x;
    const int lane = t & 63;
    const int wid  = t >> 6;
    const int quad = lane >> 4;
    const int l16  = lane & 15;
    short* Hw = Hs[wid];

    const float* w1p[2] = {sw1, vw1};
    const float* b1p[2] = {sb1, vb1};
    const float* w2p[2] = {sw2, vw2};
    const float* b2p[2] = {sb2, vb2};

    // ---- weight B-frags resident in VGPRs ----
    bf16x8 w1f[2][4];
    bf16x8 w2f[2][2][4];
    float  b1v[2][4], b2v[2][4];
    #pragma unroll
    for (int m = 0; m < 2; ++m) {
        #pragma unroll
        for (int nt = 0; nt < 4; ++nt) {
            const int col = nt * 16 + l16;
            #pragma unroll
            for (int j = 0; j < 8; ++j)
                w1f[m][nt][j] = (short)f2bf(w1p[m][(quad * 8 + j) * HIDDEN + col]);
            #pragma unroll
            for (int kk = 0; kk < 2; ++kk) {
                #pragma unroll
                for (int j = 0; j < 8; ++j)
                    w2f[m][kk][nt][j] = (short)f2bf(w2p[m][(kk * 32 + quad * 8 + j) * HIDDEN + col]);
            }
            b1v[m][nt] = b1p[m][col];
            b2v[m][nt] = b2p[m][col];
        }
    }

    const int wave_g = blockIdx.x * 4 + wid;
    const int nwaves = gridDim.x * 4;

    for (int c = wave_g; c < nchunks; c += nwaves) {
        const int j0 = c * 64;

        // ---- A-frags: 64 CSR slots -> gathered edge rows (L3-resident) ----
        bf16x8 af[4];
        #pragma unroll
        for (int mt = 0; mt < 4; ++mt) {
            int p = j0 + mt * 16 + l16;
            if (p >= E) p = E - 1;
            const int e = eperm[p];
            const float* r = edge_length + (size_t)e * NB + quad * 8;
            float4 u0 = *(const float4*)r;
            float4 u1 = *(const float4*)(r + 4);
            af[mt][0] = (short)f2bf(u0.x); af[mt][1] = (short)f2bf(u0.y);
            af[mt][2] = (short)f2bf(u0.z); af[mt][3] = (short)f2bf(u0.w);
            af[mt][4] = (short)f2bf(u1.x); af[mt][5] = (short)f2bf(u1.y);
            af[mt][6] = (short)f2bf(u1.z); af[mt][7] = (short)f2bf(u1.w);
        }

        #pragma unroll
        for (int m = 0; m < 2; ++m) {
            // ---- layer 1 + SiLU -> LDS bf16 ----
            #pragma unroll
            for (int mt = 0; mt < 4; ++mt) {
                #pragma unroll
                for (int nt = 0; nt < 4; ++nt) {
                    f32x4 cf = {b1v[m][nt], b1v[m][nt], b1v[m][nt], b1v[m][nt]};
                    cf = __builtin_amdgcn_mfma_f32_16x16x32_bf16(af[mt], w1f[m][nt], cf, 0, 0, 0);
                    #pragma unroll
                    for (int r4 = 0; r4 < 4; ++r4) {
                        float x = cf[r4];
                        // silu via fast rcp: result is rounded to bf16 anyway
                        x = x * __builtin_amdgcn_rcpf(1.0f + __expf(-x));
                        const int row = mt * 16 + quad * 4 + r4;
                        Hw[row * HSTR + nt * 16 + l16] = (short)f2bf(x);
                    }
                }
            }

            // ---- layer 2 -> LDS bf16 ----
            #pragma unroll
            for (int mt = 0; mt < 4; ++mt) {
                const int arow = mt * 16 + l16;
                bf16x8 a0 = *(const bf16x8*)(Hw + arow * HSTR + quad * 8);
                bf16x8 a1 = *(const bf16x8*)(Hw + arow * HSTR + 32 + quad * 8);
                #pragma unroll
                for (int nt = 0; nt < 4; ++nt) {
                    f32x4 cf = {b2v[m][nt], b2v[m][nt], b2v[m][nt], b2v[m][nt]};
                    cf = __builtin_amdgcn_mfma_f32_16x16x32_bf16(a1, w2f[m][1][nt], cf, 0, 0, 0);
                    cf = __builtin_amdgcn_mfma_f32_16x16x32_bf16(a0, w2f[m][0][nt], cf, 0, 0, 0);
                    #pragma unroll
                    for (int r4 = 0; r4 < 4; ++r4) {
                        const int row = mt * 16 + quad * 4 + r4;
                        Hw[row * HSTR + nt * 16 + l16] = (short)f2bf(cf[r4]);
                    }
                }
            }

            // ---- store: 8 lanes per edge row, 16 B/lane, SEQUENTIAL dest ----
            #pragma unroll
            for (int i = 0; i < 8; ++i) {
                const int row = i * 8 + (lane >> 3);
                bf16x8 v = *(const bf16x8*)(Hw + row * HSTR + (lane & 7) * 8);
                if (j0 + row < E)
                    *(bf16x8*)(W + (size_t)(j0 + row) * 128 + m * 64 + (lane & 7) * 8) = v;
            }
        }
    }
}

// ---------------------------------------------------------------------------
// Phase B (bf16 feat path): one wave per node; 1-ahead prefetch with the
// cols pointer-chase removed (chunk-coalesced cols load + __shfl broadcast).
// Verbatim round 5 (node dropped below the 73 us top-5 cutoff).
// ---------------------------------------------------------------------------
__global__ __launch_bounds__(256) void node_kernel_feat(
    const ushort4* __restrict__ feat,       // [N*64] bf16 {s,v0,v1,v2}
    const int* __restrict__ offsets,        // [N+1]
    const int* __restrict__ cols,           // [E] source column per CSR slot
    const unsigned short* __restrict__ W,   // [E,128] bf16, CSR order
    float* __restrict__ out_scalar,
    float* __restrict__ out_vector,
    int N)
{
    const int lane = threadIdx.x & 63;
    const int wave = blockIdx.x * 4 + (threadIdx.x >> 6);
    const int nw   = gridDim.x * 4;

    for (int n = wave; n < N; n += nw) {
        const int beg = offsets[n];
        const int end = offsets[n + 1];

        float as = 0.0f, a0 = 0.0f, a1 = 0.0f, a2 = 0.0f;

        for (int base = beg; base < end; base += 64) {
            const int cnt = (end - base < 64) ? (end - base) : 64;

            // one coalesced load per chunk: lane's CSR column
            int mycol = 0;
            if (lane < cnt) mycol = cols[base + lane];

            // prologue: edge k=0
            const int c0 = __shfl(mycol, 0, 64);
            const unsigned short* wp0 = W + (size_t)base * 128;
            float ws = bf2f(wp0[lane]);
            float wv = bf2f(wp0[64 + lane]);
            ushort4 f = feat[(size_t)c0 * 64 + lane];

            for (int k = 0; k < cnt; ++k) {
                const int kn = (k + 1 < cnt) ? k + 1 : k;
                const int cn = __shfl(mycol, kn, 64);
                const unsigned short* wpn = W + (size_t)(base + kn) * 128;
                const float wsn = bf2f(wpn[lane]);
                const float wvn = bf2f(wpn[64 + lane]);
                const ushort4 fn = feat[(size_t)cn * 64 + lane];

                as = fmaf(bf2f(f.x), ws, as);
                a0 = fmaf(bf2f(f.y), wv, a0);
                a1 = fmaf(bf2f(f.z), wv, a1);
                a2 = fmaf(bf2f(f.w), wv, a2);

                ws = wsn; wv = wvn; f = fn;
            }
        }

        out_scalar[(size_t)n * HIDDEN + lane] = as;
        float* ov = out_vector + (size_t)n * 3 * HIDDEN;
        ov[lane]       = a0;
        ov[64 + lane]  = a1;
        ov[128 + lane] = a2;
    }
}

// Fallback (fp32 feature gathers) if workspace can't hold the feat table.
__global__ __launch_bounds__(256) void node_kernel_f32(
    const float* __restrict__ scalar,
    const float* __restrict__ vector,
    const int* __restrict__ offsets,
    const int* __restrict__ cols,
    const unsigned short* __restrict__ W,
    float* __restrict__ out_scalar,
    float* __restrict__ out_vector,
    int N)
{
    const int lane = threadIdx.x & 63;
    const int wave = blockIdx.x * 4 + (threadIdx.x >> 6);
    const int nw   = gridDim.x * 4;

    for (int n = wave; n < N; n += nw) {
        const int beg = offsets[n];
        const int end = offsets[n + 1];
        float as = 0.0f, a0 = 0.0f, a1 = 0.0f, a2 = 0.0f;
        for (int j = beg; j < end; ++j) {
            const unsigned short* wp = W + (size_t)j * 128;
            const float w_s = bf2f(wp[lane]);
            const float w_v = bf2f(wp[64 + lane]);
            const int c = cols[j];
            const float* sp = scalar + (size_t)c * HIDDEN;
            const float* vp = vector + (size_t)c * 3 * HIDDEN;
            as = fmaf(sp[lane],       w_s, as);
            a0 = fmaf(vp[lane],       w_v, a0);
            a1 = fmaf(vp[64 + lane],  w_v, a1);
            a2 = fmaf(vp[128 + lane], w_v, a2);
        }
        out_scalar[(size_t)n * HIDDEN + lane] = as;
        float* ov = out_vector + (size_t)n * 3 * HIDDEN;
        ov[lane]       = a0;
        ov[64 + lane]  = a1;
        ov[128 + lane] = a2;
    }
}

extern "C" void kernel_launch(void* const* d_in, const int* in_sizes, int n_in,
                              void* d_out, int out_size, void* d_ws, size_t ws_size,
                              hipStream_t stream) {
    const float* scalar      = (const float*)d_in[0];
    const float* vector      = (const float*)d_in[1];
    // d_in[2] = edge_sh (unused by reference)
    const float* edge_length = (const float*)d_in[3];
    const int*   edge_index  = (const int*)d_in[4];
    const float* sw1 = (const float*)d_in[5];
    const float* sb1 = (const float*)d_in[6];
    const float* sw2 = (const float*)d_in[7];
    const float* sb2 = (const float*)d_in[8];
    const float* vw1 = (const float*)d_in[9];
    const float* vb1 = (const float*)d_in[10];
    const float* vw2 = (const float*)d_in[11];
    const float* vb2 = (const float*)d_in[12];

    const int N = in_sizes[0] / HIDDEN;       // 50000
    const int E = in_sizes[4] / 2;            // 500000

    float* out_scalar = (float*)d_out;
    float* out_vector = (float*)d_out + (size_t)N * HIDDEN;

    // ---- workspace layout ----
    size_t off = 0;
    unsigned short* W = (unsigned short*)d_ws;           // [E,128] bf16 = 128 MB
    off += (size_t)E * 128 * 2;
    int* cols = (int*)((char*)d_ws + off);               // [E]
    off += (size_t)E * 4;
    int* eperm = (int*)((char*)d_ws + off);              // [E]
    off += (size_t)E * 4;
    int* ib = (int*)((char*)d_ws + off);
    int* counts    = ib;                                  // [N]
    int* offsets   = ib + N;                              // [N+1]
    int* cursors   = ib + 2 * N + 1;                      // [N]
    int* blocksums = ib + 3 * N + 1;                      // [CS_BLOCKS]
    off += ((size_t)3 * N + 1 + CS_BLOCKS) * 4;
    off = (off + 15) & ~(size_t)15;
    ushort4* feat = (ushort4*)((char*)d_ws + off);        // [N*64] = 25.6 MB
    const bool use_feat = (off + (size_t)N * 64 * 8) <= ws_size;

    hipMemsetAsync(counts, 0, (size_t)N * sizeof(int), stream);

    const int total = N * 64;

    // featpack (x2 vectorized) + histogram
    {
        const int nthreads = total / 2;                   // total is even
        featpack_kernel<<<(nthreads + 255) / 256, 256, 0, stream>>>(
            scalar, vector, edge_index, counts, (u16x8*)feat,
            total, E, use_feat ? 1 : 0);
    }

    // scan + scatter in ONE cooperative dispatch (replaces 4 dispatches)
    {
        void* args[] = {
            (void*)&edge_index, (void*)&counts, (void*)&offsets,
            (void*)&cursors, (void*)&blocksums, (void*)&cols, (void*)&eperm,
            (void*)&N, (void*)&E
        };
        hipLaunchCooperativeKernel((void*)scan_scatter_kernel,
                                   dim3(CS_BLOCKS), dim3(CS_THREADS),
                                   args, 0, stream);
    }

    // Phase A: MLP via MFMA over CSR slots; gathered reads, sequential writes.
    const int nchunks = (E + 63) / 64;
    mlp_mfma_kernel<<<1024, 256, 0, stream>>>(
        edge_length, eperm,
        sw1, sb1, sw2, sb2, vw1, vb1, vw2, vb2,
        W, E, nchunks);

    // Phase B: sequential W streaming, chase-free gathers.
    const int ngrid = (N + 3) / 4;
    if (use_feat) {
        node_kernel_feat<<<ngrid, 256, 0, stream>>>(
            feat, offsets, cols, W, out_scalar, out_vector, N);
    } else {
        node_kernel_f32<<<ngrid, 256, 0, stream>>>(
            scalar, vector, offsets, cols, W, out_scalar, out_vector, N);
    }
}